// Round 13
// baseline (1898.832 us; speedup 1.0000x reference)
//
#include <hip/hip_runtime.h>

// GTS / DCGRU forward on gfx950. bf16 MFMA pipeline, "transposed world":
// every activation matrix is stored [(b,channel)][n] (row-major, NP=3968 cols)
// so S-applies are bt-form GEMMs: Y_t = X_t @ S^T (both operands k-contig).
//
// R13 = R12 (proven 8-phase dbuf schedule) with bt8's MFMA switched to
// v_mfma_f32_32x32x16_bf16 (2495 TF ubench vs 2176 for 16x16x32; half the
// instruction count). Stage/VMC/BARS skeleton byte-identical to R12.
// Fragment lane-maps: A/B row|col = lane&31, k = (lane>>5)*8+j;
// C/D col = lane&31, row = (reg&3) + 8*(reg>>2) + 4*(lane>>5)  [m74/m101].
// Read addr derived against the staging map: element (row r, k) of a half
// lives at (r>>4)*1024 + (r&15)*32 + (k>>5)*512 + ((k&31 & ~7) ^ (r&8?16:0))
// + (k&7)  ->  koffs[s] = (s>>1)*512 + (((s&1)^((lane>>3)&1))<<4) + ((lane>>5)<<3).

#define NN 3960
#define NP 3968
#define BB 16
#define UU 128
#define NT 62   // K-tiles of 64: 3968/64

typedef __attribute__((ext_vector_type(8))) short v8s;    // 8 x bf16
typedef __attribute__((ext_vector_type(4))) float v4f;
typedef __attribute__((ext_vector_type(16))) float v16f;

__device__ __forceinline__ float bf2f(short h) {
  union { unsigned int u; float f; } v;
  v.u = ((unsigned int)(unsigned short)h) << 16;
  return v.f;
}
__device__ __forceinline__ short f2bf(float f) {
  union { float f; unsigned int u; } v; v.f = f;
  unsigned int r = (v.u + 0x7FFFu + ((v.u >> 16) & 1u)) >> 16;
  return (short)r;
}
__device__ __forceinline__ void gld16(const void* g, void* l) {
  __builtin_amdgcn_global_load_lds(
      (const __attribute__((address_space(1))) void*)g,
      (__attribute__((address_space(3))) void*)l, 16, 0, 0);
}

// ---------------- builders ----------------

__global__ void k_rowsum(const float* __restrict__ A, float* __restrict__ out) {
  int i = blockIdx.x;
  float s = 0.f;
  for (int j = threadIdx.x; j < NN; j += 256) s += A[i * NN + j];
  __shared__ float red[256];
  red[threadIdx.x] = s; __syncthreads();
  for (int k = 128; k > 0; k >>= 1) {
    if (threadIdx.x < k) red[threadIdx.x] += red[threadIdx.x + k];
    __syncthreads();
  }
  if (threadIdx.x == 0) out[i] = red[0];
}

__global__ void k_colpart(const float* __restrict__ A, float* __restrict__ part) {
  int j = blockIdx.x * 256 + threadIdx.x;
  if (j >= NN) return;
  int p = blockIdx.y;
  int r0 = p * 495, r1 = r0 + 495;
  float s = 0.f;
  for (int i = r0; i < r1; i++) s += A[i * NN + j];
  part[p * NP + j] = s;
}

__global__ void k_inv(const float* __restrict__ rs, const float* __restrict__ part,
                      float* __restrict__ rinv, float* __restrict__ cinv) {
  int j = blockIdx.x * 256 + threadIdx.x;
  if (j >= NP) return;
  float r = 0.f, c = 0.f;
  if (j < NN) {
    r = rs[j];
    float s = 0.f;
    for (int p = 0; p < 8; p++) s += part[p * NP + j];
    c = s;
  }
  rinv[j] = (j < NN && r > 0.f) ? 1.f / r : 0.f;
  cinv[j] = (j < NN && c > 0.f) ? 1.f / c : 0.f;
}

__global__ void k_supports(const float* __restrict__ A, const float* __restrict__ rinv,
                           const float* __restrict__ cinv,
                           short* __restrict__ S0, short* __restrict__ S1) {
  __shared__ float t[32][33];
  int i0 = blockIdx.y * 32, j0 = blockIdx.x * 32;
  int tx = threadIdx.x, ty = threadIdx.y;
  #pragma unroll
  for (int q = 0; q < 4; q++) {
    int r = i0 + ty + 8 * q, c = j0 + tx;
    float a = (r < NN && c < NN) ? A[r * NN + c] : 0.f;
    t[ty + 8 * q][tx] = a;
    S1[r * NP + c] = f2bf(a * cinv[c]);
  }
  __syncthreads();
  #pragma unroll
  for (int q = 0; q < 4; q++) {
    int I = j0 + ty + 8 * q, J = i0 + tx;
    S0[I * NP + J] = f2bf(t[tx][ty + 8 * q] * rinv[J]);
  }
}

__global__ void k_buildH(const float* __restrict__ hs,
                         short* __restrict__ H0, short* __restrict__ H1) {
  __shared__ float t[32][33];
  int n0 = blockIdx.x * 32, u0 = blockIdx.y * 32;
  int bz = blockIdx.z; int b = bz & 15; int layer = bz >> 4;
  const float* src = hs + (size_t)(layer * BB + b) * NN * UU;
  short* H = layer ? H1 : H0;
  int tx = threadIdx.x, ty = threadIdx.y;
  #pragma unroll
  for (int q = 0; q < 4; q++) {
    int n = n0 + ty + 8 * q, u = u0 + tx;
    t[ty + 8 * q][tx] = (n < NN) ? src[n * UU + u] : 0.f;
  }
  __syncthreads();
  #pragma unroll
  for (int q = 0; q < 4; q++) {
    int u = u0 + ty + 8 * q, n = n0 + tx;
    H[(b * UU + u) * NP + n] = f2bf(t[tx][ty + 8 * q]);
  }
}

// X0c[r][n] = (r<16) ? bf16(inputs[r][n]) : 0   (channel-major compact, 256 rows)
__global__ void k_buildX0c(const float* __restrict__ inp, short* __restrict__ X) {
  int n = blockIdx.x * 128 + threadIdx.x;
  int row = blockIdx.y;
  float v = (row < BB && n < NN) ? inp[row * NN + n] : 0.f;
  X[row * NP + n] = f2bf(v);
}

// Wt[o][k], k-order: part-X (5*CxP), then part-H (5*128); W row = c_global*5 + m
__global__ void k_buildWt(const float* __restrict__ W, short* __restrict__ Wt,
                          int O, int KL, int CxP, int Cx) {
  int idx = blockIdx.x * 256 + threadIdx.x;
  if (idx >= O * KL) return;
  int o = idx / KL, k = idx % KL;
  int KX = 5 * CxP;
  float v = 0.f;
  if (k < KX) {
    int m = k / CxP, c = k % CxP;
    if (c < Cx) v = W[(c * 5 + m) * O + o];
  } else {
    int kl = k - KX; int m = kl >> 7, u = kl & 127;
    v = W[((Cx + u) * 5 + m) * O + o];
  }
  Wt[o * KL + k] = f2bf(v);
}

// ---------------- 256x256 8-phase bt GEMM, 32x32x16 MFMA ----------------
struct Bt8Args {
  const short* A[4];
  short* Y[4];
  const short* SUB[4];
  int mr[4];
};

__launch_bounds__(512, 2)
__global__ void k_gemm_bt8(Bt8Args P, const short* __restrict__ T0,
                           const short* __restrict__ T1) {
  int z = blockIdx.z;
  int l = blockIdx.x + (blockIdx.y << 3);   // [0,128): XCD = l&7
  int bx = l >> 4;
  int by = ((l & 7) << 1) + ((l >> 3) & 1);
  int row0 = bx * 256;
  if (row0 >= P.mr[z]) return;
  const short* Ag = P.A[z];
  short* Cg = P.Y[z];
  const short* X0 = P.SUB[z];
  const short* Bg = (z & 1) ? T1 : T0;
  __shared__ short lds[65536];   // 128 KB
  int tid = threadIdx.x, lane = tid & 63, wv = tid >> 6;
  int wr = wv >> 2, wc = wv & 3;
  int col0 = by * 256;

  // ---- staging (identical to R12) ----
  int srow = wv * 16 + (lane >> 2);
  int scol = ((lane & 3) * 8) ^ ((lane >> 5) << 4);
  const short* aS0 = Ag + (size_t)(row0 + srow) * NP + scol;
  const short* aS1 = Ag + (size_t)(row0 + 128 + srow) * NP + scol;
  int br0 = col0 + srow;        if (br0 > NP - 1) br0 = NP - 1;
  int br1 = col0 + 128 + srow;  if (br1 > NP - 1) br1 = NP - 1;
  const short* bS0 = Bg + (size_t)br0 * NP + scol;
  const short* bS1 = Bg + (size_t)br1 * NP + scol;
  short* ldsA = lds + wv * 1024 + lane * 8;
  short* ldsB = lds + 32768 + wv * 1024 + lane * 8;

#define STG_A(buf, h, tau) do { const short* _s = ((h) ? aS1 : aS0) + (tau) * 64; \
    gld16(_s,      ldsA + (buf) * 16384 + (h) * 8192); \
    gld16(_s + 32, ldsA + (buf) * 16384 + (h) * 8192 + 512); } while (0)
#define STG_B(buf, h, tau) do { const short* _s = ((h) ? bS1 : bS0) + (tau) * 64; \
    gld16(_s,      ldsB + (buf) * 16384 + (h) * 8192); \
    gld16(_s + 32, ldsB + (buf) * 16384 + (h) * 8192 + 512); } while (0)

  // ---- 32x32x16 fragment read bases ----
  // lane -> row/col = lane&31, k-chunk = (lane>>5)*8; swizzle flips bit4 of
  // the intra-32 k offset iff (lane&8).
  int kx = (lane >> 3) & 1;
  int koffs[4];
  #pragma unroll
  for (int s = 0; s < 4; s++)
    koffs[s] = (s >> 1) * 512 + (((s & 1) ^ kx) << 4) + ((lane >> 5) << 3);
  int aB0 = wr * 8192 + ((lane >> 4) & 1) * 1024 + (lane & 15) * 32;
  int bB0 = 32768 + (wc >> 1) * 8192 + (wc & 1) * 4096 +
            ((lane >> 4) & 1) * 1024 + (lane & 15) * 32;

  v16f acc[4][2];
  #pragma unroll
  for (int i = 0; i < 4; i++)
    #pragma unroll
    for (int j = 0; j < 2; j++)
      #pragma unroll
      for (int q = 0; q < 16; q++) acc[i][j][q] = 0.f;

  v8s afr[2][4], bfr0[4], bfr1[4];

#define RD32_A(b, mp) do { _Pragma("unroll") \
  for (int m2 = 0; m2 < 2; m2++) { _Pragma("unroll") \
    for (int s = 0; s < 4; s++) \
      afr[m2][s] = *(const v8s*)&lds[aB0 + (b) * 16384 + ((mp) * 2 + m2) * 2048 + koffs[s]]; } } while (0)
#define RD32_B(b, ni, DST) do { _Pragma("unroll") \
  for (int s = 0; s < 4; s++) \
    DST[s] = *(const v8s*)&lds[bB0 + (b) * 16384 + (ni) * 2048 + koffs[s]]; } while (0)
#define MM32(mp, ni, BF) do { __builtin_amdgcn_s_setprio(1); \
  _Pragma("unroll") for (int m2 = 0; m2 < 2; m2++) \
  _Pragma("unroll") for (int s = 0; s < 4; s++) \
    acc[(mp) * 2 + m2][ni] = __builtin_amdgcn_mfma_f32_32x32x16_bf16( \
        afr[m2][s], BF[s], acc[(mp) * 2 + m2][ni], 0, 0, 0); \
  __builtin_amdgcn_s_setprio(0); } while (0)
#define BARS do { __builtin_amdgcn_s_barrier(); __builtin_amdgcn_sched_barrier(0); } while (0)
#define VMC(n) asm volatile("s_waitcnt vmcnt(" #n ")" ::: "memory")

  // ---- prologue (identical stage/VMC ledger to R12) ----
  STG_A(0, 0, 0); STG_A(0, 1, 0); STG_B(0, 0, 0); STG_B(0, 1, 0);
  STG_A(1, 0, 1); STG_B(1, 0, 1); STG_B(1, 1, 1);
  VMC(6);
  BARS;

  for (int it = 0; it < NT / 2; it++) {
    int t = 2 * it;
    int st1 = t + 1;
    int st2 = t + 2 > NT - 1 ? NT - 1 : t + 2;
    int st3 = t + 3 > NT - 1 ? NT - 1 : t + 3;
    // P1: quadrant (mi 0-1, ni 0) of tile t
    RD32_A(0, 0); RD32_B(0, 0, bfr0); STG_A(1, 1, st1); BARS; MM32(0, 0, bfr0); BARS;
    // P2: (mi 0-1, ni 1)
    RD32_B(0, 1, bfr1); BARS; MM32(0, 1, bfr1); BARS;
    // P3: (mi 2-3, ni 0)
    RD32_A(0, 1); STG_B(0, 0, st2); BARS; MM32(1, 0, bfr0); BARS;
    // P4: (mi 2-3, ni 1)
    STG_B(0, 1, st2); VMC(4); BARS; MM32(1, 1, bfr1); BARS;
    // P5-P8: tile t+1 (buf1)
    RD32_A(1, 0); RD32_B(1, 0, bfr0); STG_A(0, 0, st2); BARS; MM32(0, 0, bfr0); BARS;
    RD32_B(1, 1, bfr1); STG_A(0, 1, st2); BARS; MM32(0, 1, bfr1); BARS;
    RD32_A(1, 1); STG_B(1, 0, st3); BARS; MM32(1, 0, bfr0); BARS;
    STG_B(1, 1, st3); STG_A(1, 0, st3); VMC(6); BARS; MM32(1, 1, bfr1); BARS;
  }

  // ---- epilogue: C/D map col=lane&31, row=(q&3)+8*(q>>2)+4*(lane>>5) ----
  int cheb = X0 != nullptr;
  #pragma unroll
  for (int mi = 0; mi < 4; mi++)
    #pragma unroll
    for (int ni = 0; ni < 2; ni++) {
      int col = col0 + wc * 64 + ni * 32 + (lane & 31);
      if (col < NP) {
        #pragma unroll
        for (int q = 0; q < 16; q++) {
          int row = row0 + wr * 128 + mi * 32 + (q & 3) + 8 * (q >> 2) + 4 * (lane >> 5);
          float v = acc[mi][ni][q];
          if (cheb) v = 2.f * v - bf2f(X0[(size_t)row * NP + col]);
          Cg[(size_t)row * NP + col] = f2bf(v);
        }
      }
    }
#undef STG_A
#undef STG_B
#undef RD32_A
#undef RD32_B
#undef MM32
#undef BARS
#undef VMC
}

// ---------------- W-projection GEMM (block-XOR LDS staging) ----------------
__launch_bounds__(256, 2)
__global__ void k_gemm_wt(const short* __restrict__ Wt, int KL, int KX, int CxP,
                          int bsx,
                          const short* __restrict__ pX0, const short* __restrict__ pX1,
                          const short* __restrict__ pX2, const short* __restrict__ pX3,
                          const short* __restrict__ pX4,
                          const short* __restrict__ pH0, const short* __restrict__ pH1,
                          const short* __restrict__ pH2, const short* __restrict__ pH3,
                          const short* __restrict__ pH4,
                          const float* __restrict__ bias, const short* __restrict__ H,
                          short* __restrict__ Ut, short* __restrict__ out0, int epi) {
  __shared__ short lA[128 * 32];
  __shared__ short lB[128 * 40];
  int tid = threadIdx.x, lane = tid & 63, w = tid >> 6;
  int n0 = blockIdx.x * 128;
  int oy = blockIdx.y;
  int b = blockIdx.z;
  int arow = w * 16 + (lane >> 2), koff = (lane & 3) * 8;
  const short* wa0 = Wt + (oy * 128 + arow) * KL + koff;
  const short* wa1 = Wt + (oy * 128 + 64 + arow) * KL + koff;
  short* la0 = lA + w * 512 + lane * 8;
  short* la1 = lA + 2048 + w * 512 + lane * 8;
  int srow = tid >> 3, c16 = (tid & 7) * 16;
  int sk7 = srow & 7, sk3 = srow >> 3;
  int wr = (w >> 1) * 64, wc = (w & 1) * 64;
  v4f acc[4][4];
  #pragma unroll
  for (int i = 0; i < 4; i++)
    #pragma unroll
    for (int j = 0; j < 4; j++) {
      acc[i][j][0] = 0.f; acc[i][j][1] = 0.f; acc[i][j][2] = 0.f; acc[i][j][3] = 0.f;
    }
  int KT = KL >> 5;
  for (int kt = 0; kt < KT; kt++) {
    int kb = kt * 32;
    const short* src;
    if (kb < KX) {
      int m = kb / CxP, c0 = kb % CxP;
      const short* base = m == 0 ? pX0 : m == 1 ? pX1 : m == 2 ? pX2 : m == 3 ? pX3 : pX4;
      src = base + (b * bsx + c0) * NP;
    } else {
      int kl = kb - KX; int m = kl >> 7, c0 = kl & 127;
      const short* base = m == 0 ? pH0 : m == 1 ? pH1 : m == 2 ? pH2 : m == 3 ? pH3 : pH4;
      src = base + (b * UU + c0) * NP;
    }
    __syncthreads();
    gld16(wa0 + kb, la0); gld16(wa1 + kb, la1);
    const v8s* p = (const v8s*)(src + srow * NP + n0 + c16);
    v8s v0 = p[0], v1 = p[1];
    #pragma unroll
    for (int j = 0; j < 8; j++) {
      int cA = c16 + j, cB = c16 + 8 + j;
      lB[cA * 40 + sk7 + 8 * ((sk3 ^ (cA >> 4)) & 3)] = v0[j];
      lB[cB * 40 + sk7 + 8 * ((sk3 ^ (cB >> 4)) & 3)] = v1[j];
    }
    __syncthreads();
    v8s af[4], bfv[4];
    #pragma unroll
    for (int mi = 0; mi < 4; mi++)
      af[mi] = *(const v8s*)&lA[(wr + mi * 16 + (lane & 15)) * 32 + (lane >> 4) * 8];
    #pragma unroll
    for (int ni = 0; ni < 4; ni++) {
      int colb = wc + ni * 16 + (lane & 15);
      bfv[ni] = *(const v8s*)&lB[colb * 40 + 8 * (((lane >> 4) ^ (colb >> 4)) & 3)];
    }
    #pragma unroll
    for (int mi = 0; mi < 4; mi++)
      #pragma unroll
      for (int ni = 0; ni < 4; ni++)
        acc[mi][ni] = __builtin_amdgcn_mfma_f32_16x16x32_bf16(af[mi], bfv[ni], acc[mi][ni], 0, 0, 0);
  }
  #pragma unroll
  for (int mi = 0; mi < 4; mi++)
    #pragma unroll
    for (int ni = 0; ni < 4; ni++) {
      int col = n0 + wc + ni * 16 + (lane & 15);
      #pragma unroll
      for (int r = 0; r < 4; r++) {
        int o = oy * 128 + wr + mi * 16 + (lane >> 4) * 4 + r;
        float v = acc[mi][ni][r] + bias[o];
        if (epi == 0) {
          float s = 1.f / (1.f + __expf(-v));
          if (o < UU) {
            int idx = (b * UU + o) * NP + col;
            out0[idx] = f2bf(s * bf2f(H[idx]));
          } else {
            int idx = (b * UU + (o - UU)) * NP + col;
            Ut[idx] = f2bf(s);
          }
        } else {
          float cv = tanhf(v);
          int idx = (b * UU + o) * NP + col;
          float u = bf2f(Ut[idx]), h = bf2f(H[idx]);
          out0[idx] = f2bf(u * h + (1.f - u) * cv);
        }
      }
    }
}

__global__ void k_proj(const short* __restrict__ nh, const float* __restrict__ Wp,
                       const float* __restrict__ bp, float* __restrict__ out) {
  int n = blockIdx.x * 256 + threadIdx.x;
  int b = blockIdx.y;
  if (n >= NN) return;
  float acc = bp[0];
  #pragma unroll 8
  for (int u = 0; u < UU; u++)
    acc += bf2f(nh[(b * UU + u) * NP + n]) * Wp[u];
  out[b * NN + n] = acc;
}

__global__ void k_bail(float* out, int n, float val) {
  int i = blockIdx.x * 256 + threadIdx.x;
  if (i < n) out[i] = val;
}

// ---------------- host ----------------

extern "C" void kernel_launch(void* const* d_in, const int* in_sizes, int n_in,
                              void* d_out, int out_size, void* d_ws, size_t ws_size,
                              hipStream_t stream) {
  const float* inp = (const float*)d_in[0];
  const float* adj = (const float*)d_in[1];
  const float* hid = (const float*)d_in[2];
  const float* Wg0 = (const float*)d_in[4];
  const float* bg0 = (const float*)d_in[5];
  const float* Wc0 = (const float*)d_in[6];
  const float* bc0 = (const float*)d_in[7];
  const float* Wg1 = (const float*)d_in[8];
  const float* bg1 = (const float*)d_in[9];
  const float* Wc1 = (const float*)d_in[10];
  const float* bc1 = (const float*)d_in[11];
  const float* Wp = (const float*)d_in[12];
  const float* bp = (const float*)d_in[13];
  float* out = (float*)d_out;

  const size_t SZ_S = (size_t)NP * NP * 2;
  const size_t SZ_M = (size_t)2048 * NP * 2;
  const size_t SZ_MS = (size_t)512 * NP * 2;

  size_t o_S0 = 0;
  size_t o_S1 = o_S0 + SZ_S;
  size_t o_H0 = o_S1 + SZ_S;
  size_t o_H1 = o_H0 + SZ_M;
  size_t o_Ut = o_H1 + SZ_M;
  size_t o_Xrh = o_Ut + SZ_M;
  size_t o_nh0 = o_Xrh + SZ_M;
  size_t o_YB = o_nh0 + SZ_M;
  size_t o_YX123 = o_YB + 4 * SZ_M;
  size_t o_X0c = o_YX123;
  size_t o_YS = o_X0c + SZ_MS;
  size_t o_Wg0t = o_YX123 + 3 * SZ_M;
  size_t o_Wc0t = o_Wg0t + (size_t)256 * 800 * 2;
  size_t o_Wg1t = o_Wc0t + (size_t)128 * 800 * 2;
  size_t o_Wc1t = o_Wg1t + (size_t)256 * 1280 * 2;
  size_t o_rinv = o_Wc1t + (size_t)128 * 1280 * 2;
  size_t o_cinv = o_rinv + NP * 4;
  size_t o_rs = o_cinv + NP * 4;
  size_t o_part = o_rs + NP * 4;
  size_t NEED = o_part + (size_t)8 * NP * 4;

  if (ws_size < NEED) {
    float v = -(float)(double)(ws_size >> 20);
    k_bail<<<(out_size + 255) / 256, 256, 0, stream>>>(out, out_size, v);
    return;
  }

  char* w = (char*)d_ws;
  short* S0 = (short*)(w + o_S0);
  short* S1 = (short*)(w + o_S1);
  short* H0 = (short*)(w + o_H0);
  short* H1 = (short*)(w + o_H1);
  short* Ut = (short*)(w + o_Ut);
  short* Xrh = (short*)(w + o_Xrh);
  short* nh0 = (short*)(w + o_nh0);
  short* nh1 = Ut;
  short* YB[4];
  for (int i = 0; i < 4; i++) YB[i] = (short*)(w + o_YB + i * SZ_M);
  short* YXa = H0;
  short* YXb = (short*)(w + o_YX123 + 0 * SZ_M);
  short* YXc = (short*)(w + o_YX123 + 1 * SZ_M);
  short* YXd = (short*)(w + o_YX123 + 2 * SZ_M);
  short* YS[4];
  for (int i = 0; i < 4; i++) YS[i] = (short*)(w + o_YS + i * SZ_MS);
  short* X0c = (short*)(w + o_X0c);
  short* Wg0t = (short*)(w + o_Wg0t);
  short* Wc0t = (short*)(w + o_Wc0t);
  short* Wg1t = (short*)(w + o_Wg1t);
  short* Wc1t = (short*)(w + o_Wc1t);
  float* rinv = (float*)(w + o_rinv);
  float* cinv = (float*)(w + o_cinv);
  float* rs = (float*)(w + o_rs);
  float* part = (float*)(w + o_part);

  k_rowsum<<<NN, 256, 0, stream>>>(adj, rs);
  k_colpart<<<dim3(16, 8), 256, 0, stream>>>(adj, part);
  k_inv<<<16, 256, 0, stream>>>(rs, part, rinv, cinv);
  k_supports<<<dim3(124, 124), dim3(32, 8), 0, stream>>>(adj, rinv, cinv, S0, S1);
  k_buildH<<<dim3(124, 4, 32), dim3(32, 8), 0, stream>>>(hid, H0, H1);
  k_buildX0c<<<dim3(31, 256), 128, 0, stream>>>(inp, X0c);
  k_buildWt<<<(256 * 800 + 255) / 256, 256, 0, stream>>>(Wg0, Wg0t, 256, 800, 32, 1);
  k_buildWt<<<(128 * 800 + 255) / 256, 256, 0, stream>>>(Wc0, Wc0t, 128, 800, 32, 1);
  k_buildWt<<<(256 * 1280 + 255) / 256, 256, 0, stream>>>(Wg1, Wg1t, 256, 1280, 128, 128);
  k_buildWt<<<(128 * 1280 + 255) / 256, 256, 0, stream>>>(Wc1, Wc1t, 128, 1280, 128, 128);

  auto launch_bt8 = [&](const Bt8Args& a, int nz) {
    k_gemm_bt8<<<dim3(8, 16, nz), 512, 0, stream>>>(a, S0, S1);
  };

  // ---- cell 0 ---- (X diffusion on compact 256-row X0c)
  {
    Bt8Args h1 = {{X0c, X0c, H0, H0}, {YS[0], YS[2], YB[0], YB[2]},
                  {nullptr, nullptr, nullptr, nullptr}, {256, 256, 2048, 2048}};
    launch_bt8(h1, 4);
    Bt8Args h2 = {{YS[0], YS[2], YB[0], YB[2]}, {YS[1], YS[3], YB[1], YB[3]},
                  {X0c, X0c, H0, H0}, {256, 256, 2048, 2048}};
    launch_bt8(h2, 4);
  }
  k_gemm_wt<<<dim3(31, 2, 16), 256, 0, stream>>>(Wg0t, 800, 160, 32, 1,
      X0c, YS[0], YS[1], YS[2], YS[3], H0, YB[0], YB[1], YB[2], YB[3],
      bg0, H0, Ut, Xrh, 0);
  {
    Bt8Args h1 = {{Xrh, Xrh, nullptr, nullptr}, {YB[0], YB[2], nullptr, nullptr},
                  {nullptr, nullptr, nullptr, nullptr}, {2048, 2048, 0, 0}};
    launch_bt8(h1, 2);
    Bt8Args h2 = {{YB[0], YB[2], nullptr, nullptr}, {YB[1], YB[3], nullptr, nullptr},
                  {Xrh, Xrh, nullptr, nullptr}, {2048, 2048, 0, 0}};
    launch_bt8(h2, 2);
  }
  k_gemm_wt<<<dim3(31, 1, 16), 256, 0, stream>>>(Wc0t, 800, 160, 32, 1,
      X0c, YS[0], YS[1], YS[2], YS[3], Xrh, YB[0], YB[1], YB[2], YB[3],
      bc0, H0, Ut, nh0, 1);

  // ---- cell 1 ----
  {
    Bt8Args h1 = {{nh0, nh0, H1, H1}, {YXa, YXc, YB[0], YB[2]},
                  {nullptr, nullptr, nullptr, nullptr}, {2048, 2048, 2048, 2048}};
    launch_bt8(h1, 4);
    Bt8Args h2 = {{YXa, YXc, YB[0], YB[2]}, {YXb, YXd, YB[1], YB[3]},
                  {nh0, nh0, H1, H1}, {2048, 2048, 2048, 2048}};
    launch_bt8(h2, 4);
  }
  k_gemm_wt<<<dim3(31, 2, 16), 256, 0, stream>>>(Wg1t, 1280, 640, 128, 128,
      nh0, YXa, YXb, YXc, YXd, H1, YB[0], YB[1], YB[2], YB[3],
      bg1, H1, Ut, Xrh, 0);
  {
    Bt8Args h1 = {{Xrh, Xrh, nullptr, nullptr}, {YB[0], YB[2], nullptr, nullptr},
                  {nullptr, nullptr, nullptr, nullptr}, {2048, 2048, 0, 0}};
    launch_bt8(h1, 2);
    Bt8Args h2 = {{YB[0], YB[2], nullptr, nullptr}, {YB[1], YB[3], nullptr, nullptr},
                  {Xrh, Xrh, nullptr, nullptr}, {2048, 2048, 0, 0}};
    launch_bt8(h2, 2);
  }
  k_gemm_wt<<<dim3(31, 1, 16), 256, 0, stream>>>(Wc1t, 1280, 640, 128, 128,
      nh0, YXa, YXb, YXc, YXd, Xrh, YB[0], YB[1], YB[2], YB[3],
      bc1, H1, Ut, nh1, 1);

  // ---- output projection ----
  k_proj<<<dim3(16, 16), 256, 0, stream>>>(nh1, Wp, bp, out);
}

// Round 14
// 1728.554 us; speedup vs baseline: 1.0985x; 1.0985x over previous
//
#include <hip/hip_runtime.h>

// GTS / DCGRU forward on gfx950. bf16 MFMA pipeline, "transposed world":
// every activation matrix is stored [(b,channel)][n] (row-major, NP=3968 cols)
// so S-applies are bt-form GEMMs: Y_t = X_t @ S^T (both operands k-contig).
//
// R14 = exact restoration of R12 (best verified: 1732/1734 us).
//  - bt8: 256x256, BK=64, 128KB double-buffered LDS, 8-phase in-phase
//    schedule, 16x16x32 MFMA, st_16x32 swizzle (pre-swizzled global src +
//    XOR'd reads), counted vmcnt(4)/vmcnt(6), XCD-pinned col panels.
//  - compact X0c [256][NP] channel-major (rows 0-15 real, rest zeros).
//  - wt: block-XOR LDS B-staging (involution), bsx row-stride.
// Closed lines: R8 pre-barrier reads race; R9/R10 read-ahead spills
// (launch_bounds can't prevent); R11 single-buffer 2-block never co-resident;
// R13 32x32x16 shape costs 2.4e7 bank conflicts (~40us/dispatch) under this
// storage layout -> net loss.

#define NN 3960
#define NP 3968
#define BB 16
#define UU 128
#define NT 62   // K-tiles of 64: 3968/64

typedef __attribute__((ext_vector_type(8))) short v8s;   // 8 x bf16
typedef __attribute__((ext_vector_type(4))) float v4f;

__device__ __forceinline__ float bf2f(short h) {
  union { unsigned int u; float f; } v;
  v.u = ((unsigned int)(unsigned short)h) << 16;
  return v.f;
}
__device__ __forceinline__ short f2bf(float f) {
  union { float f; unsigned int u; } v; v.f = f;
  unsigned int r = (v.u + 0x7FFFu + ((v.u >> 16) & 1u)) >> 16;
  return (short)r;
}
__device__ __forceinline__ void gld16(const void* g, void* l) {
  __builtin_amdgcn_global_load_lds(
      (const __attribute__((address_space(1))) void*)g,
      (__attribute__((address_space(3))) void*)l, 16, 0, 0);
}

// ---------------- builders ----------------

__global__ void k_rowsum(const float* __restrict__ A, float* __restrict__ out) {
  int i = blockIdx.x;
  float s = 0.f;
  for (int j = threadIdx.x; j < NN; j += 256) s += A[i * NN + j];
  __shared__ float red[256];
  red[threadIdx.x] = s; __syncthreads();
  for (int k = 128; k > 0; k >>= 1) {
    if (threadIdx.x < k) red[threadIdx.x] += red[threadIdx.x + k];
    __syncthreads();
  }
  if (threadIdx.x == 0) out[i] = red[0];
}

__global__ void k_colpart(const float* __restrict__ A, float* __restrict__ part) {
  int j = blockIdx.x * 256 + threadIdx.x;
  if (j >= NN) return;
  int p = blockIdx.y;
  int r0 = p * 495, r1 = r0 + 495;
  float s = 0.f;
  for (int i = r0; i < r1; i++) s += A[i * NN + j];
  part[p * NP + j] = s;
}

__global__ void k_inv(const float* __restrict__ rs, const float* __restrict__ part,
                      float* __restrict__ rinv, float* __restrict__ cinv) {
  int j = blockIdx.x * 256 + threadIdx.x;
  if (j >= NP) return;
  float r = 0.f, c = 0.f;
  if (j < NN) {
    r = rs[j];
    float s = 0.f;
    for (int p = 0; p < 8; p++) s += part[p * NP + j];
    c = s;
  }
  rinv[j] = (j < NN && r > 0.f) ? 1.f / r : 0.f;
  cinv[j] = (j < NN && c > 0.f) ? 1.f / c : 0.f;
}

__global__ void k_supports(const float* __restrict__ A, const float* __restrict__ rinv,
                           const float* __restrict__ cinv,
                           short* __restrict__ S0, short* __restrict__ S1) {
  __shared__ float t[32][33];
  int i0 = blockIdx.y * 32, j0 = blockIdx.x * 32;
  int tx = threadIdx.x, ty = threadIdx.y;
  #pragma unroll
  for (int q = 0; q < 4; q++) {
    int r = i0 + ty + 8 * q, c = j0 + tx;
    float a = (r < NN && c < NN) ? A[r * NN + c] : 0.f;
    t[ty + 8 * q][tx] = a;
    S1[r * NP + c] = f2bf(a * cinv[c]);
  }
  __syncthreads();
  #pragma unroll
  for (int q = 0; q < 4; q++) {
    int I = j0 + ty + 8 * q, J = i0 + tx;
    S0[I * NP + J] = f2bf(t[tx][ty + 8 * q] * rinv[J]);
  }
}

__global__ void k_buildH(const float* __restrict__ hs,
                         short* __restrict__ H0, short* __restrict__ H1) {
  __shared__ float t[32][33];
  int n0 = blockIdx.x * 32, u0 = blockIdx.y * 32;
  int bz = blockIdx.z; int b = bz & 15; int layer = bz >> 4;
  const float* src = hs + (size_t)(layer * BB + b) * NN * UU;
  short* H = layer ? H1 : H0;
  int tx = threadIdx.x, ty = threadIdx.y;
  #pragma unroll
  for (int q = 0; q < 4; q++) {
    int n = n0 + ty + 8 * q, u = u0 + tx;
    t[ty + 8 * q][tx] = (n < NN) ? src[n * UU + u] : 0.f;
  }
  __syncthreads();
  #pragma unroll
  for (int q = 0; q < 4; q++) {
    int u = u0 + ty + 8 * q, n = n0 + tx;
    H[(b * UU + u) * NP + n] = f2bf(t[tx][ty + 8 * q]);
  }
}

// X0c[r][n] = (r<16) ? bf16(inputs[r][n]) : 0   (channel-major compact, 256 rows)
__global__ void k_buildX0c(const float* __restrict__ inp, short* __restrict__ X) {
  int n = blockIdx.x * 128 + threadIdx.x;
  int row = blockIdx.y;
  float v = (row < BB && n < NN) ? inp[row * NN + n] : 0.f;
  X[row * NP + n] = f2bf(v);
}

// Wt[o][k], k-order: part-X (5*CxP), then part-H (5*128); W row = c_global*5 + m
__global__ void k_buildWt(const float* __restrict__ W, short* __restrict__ Wt,
                          int O, int KL, int CxP, int Cx) {
  int idx = blockIdx.x * 256 + threadIdx.x;
  if (idx >= O * KL) return;
  int o = idx / KL, k = idx % KL;
  int KX = 5 * CxP;
  float v = 0.f;
  if (k < KX) {
    int m = k / CxP, c = k % CxP;
    if (c < Cx) v = W[(c * 5 + m) * O + o];
  } else {
    int kl = k - KX; int m = kl >> 7, u = kl & 127;
    v = W[((Cx + u) * 5 + m) * O + o];
  }
  Wt[o * KL + k] = f2bf(v);
}

// ---------------- 256x256 8-phase bt GEMM (+XCD swizzle) ----------------
struct Bt8Args {
  const short* A[4];
  short* Y[4];
  const short* SUB[4];
  int mr[4];
};

__launch_bounds__(512, 2)
__global__ void k_gemm_bt8(Bt8Args P, const short* __restrict__ T0,
                           const short* __restrict__ T1) {
  int z = blockIdx.z;
  // XCD swizzle: hw XCD = (linear wg) mod 8 (z contributes 128z = 0 mod 8).
  // Map so XCD q owns col-panels {2q, 2q+1} (4MB B in its L2).
  int l = blockIdx.x + (blockIdx.y << 3);   // [0,128)
  int bx = l >> 4;
  int by = ((l & 7) << 1) + ((l >> 3) & 1);
  int row0 = bx * 256;
  if (row0 >= P.mr[z]) return;
  const short* Ag = P.A[z];
  short* Cg = P.Y[z];
  const short* X0 = P.SUB[z];
  const short* Bg = (z & 1) ? T1 : T0;
  __shared__ short lds[65536];   // 128 KB
  int tid = threadIdx.x, lane = tid & 63, wv = tid >> 6;
  int wr = wv >> 2, wc = wv & 3;
  int col0 = by * 256;

  int srow = wv * 16 + (lane >> 2);
  int scol = ((lane & 3) * 8) ^ ((lane >> 5) << 4);
  const short* aS0 = Ag + (size_t)(row0 + srow) * NP + scol;
  const short* aS1 = Ag + (size_t)(row0 + 128 + srow) * NP + scol;
  int br0 = col0 + srow;        if (br0 > NP - 1) br0 = NP - 1;
  int br1 = col0 + 128 + srow;  if (br1 > NP - 1) br1 = NP - 1;
  const short* bS0 = Bg + (size_t)br0 * NP + scol;
  const short* bS1 = Bg + (size_t)br1 * NP + scol;
  short* ldsA = lds + wv * 1024 + lane * 8;
  short* ldsB = lds + 32768 + wv * 1024 + lane * 8;

#define STG_A(buf, h, tau) do { const short* _s = ((h) ? aS1 : aS0) + (tau) * 64; \
    gld16(_s,      ldsA + (buf) * 16384 + (h) * 8192); \
    gld16(_s + 32, ldsA + (buf) * 16384 + (h) * 8192 + 512); } while (0)
#define STG_B(buf, h, tau) do { const short* _s = ((h) ? bS1 : bS0) + (tau) * 64; \
    gld16(_s,      ldsB + (buf) * 16384 + (h) * 8192); \
    gld16(_s + 32, ldsB + (buf) * 16384 + (h) * 8192 + 512); } while (0)

  int fro = (lane & 15) * 32 + (((lane >> 4) * 8) ^ ((lane & 8) * 2));
  int aBase = wr * 8192 + fro;
  int bBase = 32768 + (wc >> 1) * 8192 + (wc & 1) * 4096 + fro;

  v4f acc[8][4];
  #pragma unroll
  for (int i = 0; i < 8; i++)
    #pragma unroll
    for (int j = 0; j < 4; j++) {
      acc[i][j][0] = 0.f; acc[i][j][1] = 0.f; acc[i][j][2] = 0.f; acc[i][j][3] = 0.f;
    }
  v8s afr[4][2], bfr[4][2];

#define RD_A(b, miB) do { _Pragma("unroll") \
  for (int m2 = 0; m2 < 4; m2++) { \
    afr[m2][0] = *(const v8s*)&lds[aBase + (b) * 16384 + ((miB) + m2) * 1024]; \
    afr[m2][1] = *(const v8s*)&lds[aBase + (b) * 16384 + ((miB) + m2) * 1024 + 512]; } } while (0)
#define RD_B(b, niB) do { _Pragma("unroll") \
  for (int n2 = 0; n2 < 2; n2++) { \
    bfr[(niB) + n2][0] = *(const v8s*)&lds[bBase + (b) * 16384 + ((niB) + n2) * 1024]; \
    bfr[(niB) + n2][1] = *(const v8s*)&lds[bBase + (b) * 16384 + ((niB) + n2) * 1024 + 512]; } } while (0)
#define MM(miB, niB) do { __builtin_amdgcn_s_setprio(1); \
  _Pragma("unroll") for (int m2 = 0; m2 < 4; m2++) \
  _Pragma("unroll") for (int n2 = 0; n2 < 2; n2++) { \
    acc[(miB) + m2][(niB) + n2] = __builtin_amdgcn_mfma_f32_16x16x32_bf16( \
        afr[m2][0], bfr[(niB) + n2][0], acc[(miB) + m2][(niB) + n2], 0, 0, 0); \
    acc[(miB) + m2][(niB) + n2] = __builtin_amdgcn_mfma_f32_16x16x32_bf16( \
        afr[m2][1], bfr[(niB) + n2][1], acc[(miB) + m2][(niB) + n2], 0, 0, 0); } \
  __builtin_amdgcn_s_setprio(0); } while (0)
#define BARS do { __builtin_amdgcn_s_barrier(); __builtin_amdgcn_sched_barrier(0); } while (0)
#define VMC(n) asm volatile("s_waitcnt vmcnt(" #n ")" ::: "memory")

  STG_A(0, 0, 0); STG_A(0, 1, 0); STG_B(0, 0, 0); STG_B(0, 1, 0);
  STG_A(1, 0, 1); STG_B(1, 0, 1); STG_B(1, 1, 1);
  VMC(6);
  BARS;

  for (int it = 0; it < NT / 2; it++) {
    int t = 2 * it;
    int st1 = t + 1;
    int st2 = t + 2 > NT - 1 ? NT - 1 : t + 2;
    int st3 = t + 3 > NT - 1 ? NT - 1 : t + 3;
    RD_A(0, 0); RD_B(0, 0); STG_A(1, 1, st1); BARS; MM(0, 0); BARS;
    RD_B(0, 2); BARS; MM(0, 2); BARS;
    RD_A(0, 4); STG_B(0, 0, st2); BARS; MM(4, 0); BARS;
    STG_B(0, 1, st2); VMC(4); BARS; MM(4, 2); BARS;
    RD_A(1, 0); RD_B(1, 0); STG_A(0, 0, st2); BARS; MM(0, 0); BARS;
    RD_B(1, 2); STG_A(0, 1, st2); BARS; MM(0, 2); BARS;
    RD_A(1, 4); STG_B(1, 0, st3); BARS; MM(4, 0); BARS;
    STG_B(1, 1, st3); STG_A(1, 0, st3); VMC(6); BARS; MM(4, 2); BARS;
  }

  int cheb = X0 != nullptr;
  #pragma unroll
  for (int mi = 0; mi < 8; mi++)
    #pragma unroll
    for (int ni = 0; ni < 4; ni++) {
      int col = col0 + wc * 64 + ni * 16 + (lane & 15);
      if (col < NP) {
        #pragma unroll
        for (int r = 0; r < 4; r++) {
          int row = row0 + wr * 128 + mi * 16 + (lane >> 4) * 4 + r;
          float v = acc[mi][ni][r];
          if (cheb) v = 2.f * v - bf2f(X0[(size_t)row * NP + col]);
          Cg[(size_t)row * NP + col] = f2bf(v);
        }
      }
    }
#undef STG_A
#undef STG_B
#undef RD_A
#undef RD_B
#undef MM
#undef BARS
#undef VMC
}

// ---------------- W-projection GEMM (block-XOR LDS staging) ----------------
__launch_bounds__(256, 2)
__global__ void k_gemm_wt(const short* __restrict__ Wt, int KL, int KX, int CxP,
                          int bsx,
                          const short* __restrict__ pX0, const short* __restrict__ pX1,
                          const short* __restrict__ pX2, const short* __restrict__ pX3,
                          const short* __restrict__ pX4,
                          const short* __restrict__ pH0, const short* __restrict__ pH1,
                          const short* __restrict__ pH2, const short* __restrict__ pH3,
                          const short* __restrict__ pH4,
                          const float* __restrict__ bias, const short* __restrict__ H,
                          short* __restrict__ Ut, short* __restrict__ out0, int epi) {
  __shared__ short lA[128 * 32];
  __shared__ short lB[128 * 40];
  int tid = threadIdx.x, lane = tid & 63, w = tid >> 6;
  int n0 = blockIdx.x * 128;
  int oy = blockIdx.y;
  int b = blockIdx.z;
  int arow = w * 16 + (lane >> 2), koff = (lane & 3) * 8;
  const short* wa0 = Wt + (oy * 128 + arow) * KL + koff;
  const short* wa1 = Wt + (oy * 128 + 64 + arow) * KL + koff;
  short* la0 = lA + w * 512 + lane * 8;
  short* la1 = lA + 2048 + w * 512 + lane * 8;
  int srow = tid >> 3, c16 = (tid & 7) * 16;
  int sk7 = srow & 7, sk3 = srow >> 3;
  int wr = (w >> 1) * 64, wc = (w & 1) * 64;
  v4f acc[4][4];
  #pragma unroll
  for (int i = 0; i < 4; i++)
    #pragma unroll
    for (int j = 0; j < 4; j++) {
      acc[i][j][0] = 0.f; acc[i][j][1] = 0.f; acc[i][j][2] = 0.f; acc[i][j][3] = 0.f;
    }
  int KT = KL >> 5;
  for (int kt = 0; kt < KT; kt++) {
    int kb = kt * 32;
    const short* src;
    if (kb < KX) {
      int m = kb / CxP, c0 = kb % CxP;
      const short* base = m == 0 ? pX0 : m == 1 ? pX1 : m == 2 ? pX2 : m == 3 ? pX3 : pX4;
      src = base + (b * bsx + c0) * NP;
    } else {
      int kl = kb - KX; int m = kl >> 7, c0 = kl & 127;
      const short* base = m == 0 ? pH0 : m == 1 ? pH1 : m == 2 ? pH2 : m == 3 ? pH3 : pH4;
      src = base + (b * UU + c0) * NP;
    }
    __syncthreads();
    gld16(wa0 + kb, la0); gld16(wa1 + kb, la1);
    const v8s* p = (const v8s*)(src + srow * NP + n0 + c16);
    v8s v0 = p[0], v1 = p[1];
    #pragma unroll
    for (int j = 0; j < 8; j++) {
      int cA = c16 + j, cB = c16 + 8 + j;
      lB[cA * 40 + sk7 + 8 * ((sk3 ^ (cA >> 4)) & 3)] = v0[j];
      lB[cB * 40 + sk7 + 8 * ((sk3 ^ (cB >> 4)) & 3)] = v1[j];
    }
    __syncthreads();
    v8s af[4], bfv[4];
    #pragma unroll
    for (int mi = 0; mi < 4; mi++)
      af[mi] = *(const v8s*)&lA[(wr + mi * 16 + (lane & 15)) * 32 + (lane >> 4) * 8];
    #pragma unroll
    for (int ni = 0; ni < 4; ni++) {
      int colb = wc + ni * 16 + (lane & 15);
      bfv[ni] = *(const v8s*)&lB[colb * 40 + 8 * (((lane >> 4) ^ (colb >> 4)) & 3)];
    }
    #pragma unroll
    for (int mi = 0; mi < 4; mi++)
      #pragma unroll
      for (int ni = 0; ni < 4; ni++)
        acc[mi][ni] = __builtin_amdgcn_mfma_f32_16x16x32_bf16(af[mi], bfv[ni], acc[mi][ni], 0, 0, 0);
  }
  #pragma unroll
  for (int mi = 0; mi < 4; mi++)
    #pragma unroll
    for (int ni = 0; ni < 4; ni++) {
      int col = n0 + wc + ni * 16 + (lane & 15);
      #pragma unroll
      for (int r = 0; r < 4; r++) {
        int o = oy * 128 + wr + mi * 16 + (lane >> 4) * 4 + r;
        float v = acc[mi][ni][r] + bias[o];
        if (epi == 0) {
          float s = 1.f / (1.f + __expf(-v));
          if (o < UU) {
            int idx = (b * UU + o) * NP + col;
            out0[idx] = f2bf(s * bf2f(H[idx]));
          } else {
            int idx = (b * UU + (o - UU)) * NP + col;
            Ut[idx] = f2bf(s);
          }
        } else {
          float cv = tanhf(v);
          int idx = (b * UU + o) * NP + col;
          float u = bf2f(Ut[idx]), h = bf2f(H[idx]);
          out0[idx] = f2bf(u * h + (1.f - u) * cv);
        }
      }
    }
}

__global__ void k_proj(const short* __restrict__ nh, const float* __restrict__ Wp,
                       const float* __restrict__ bp, float* __restrict__ out) {
  int n = blockIdx.x * 256 + threadIdx.x;
  int b = blockIdx.y;
  if (n >= NN) return;
  float acc = bp[0];
  #pragma unroll 8
  for (int u = 0; u < UU; u++)
    acc += bf2f(nh[(b * UU + u) * NP + n]) * Wp[u];
  out[b * NN + n] = acc;
}

__global__ void k_bail(float* out, int n, float val) {
  int i = blockIdx.x * 256 + threadIdx.x;
  if (i < n) out[i] = val;
}

// ---------------- host ----------------

extern "C" void kernel_launch(void* const* d_in, const int* in_sizes, int n_in,
                              void* d_out, int out_size, void* d_ws, size_t ws_size,
                              hipStream_t stream) {
  const float* inp = (const float*)d_in[0];
  const float* adj = (const float*)d_in[1];
  const float* hid = (const float*)d_in[2];
  const float* Wg0 = (const float*)d_in[4];
  const float* bg0 = (const float*)d_in[5];
  const float* Wc0 = (const float*)d_in[6];
  const float* bc0 = (const float*)d_in[7];
  const float* Wg1 = (const float*)d_in[8];
  const float* bg1 = (const float*)d_in[9];
  const float* Wc1 = (const float*)d_in[10];
  const float* bc1 = (const float*)d_in[11];
  const float* Wp = (const float*)d_in[12];
  const float* bp = (const float*)d_in[13];
  float* out = (float*)d_out;

  const size_t SZ_S = (size_t)NP * NP * 2;
  const size_t SZ_M = (size_t)2048 * NP * 2;
  const size_t SZ_MS = (size_t)512 * NP * 2;

  size_t o_S0 = 0;
  size_t o_S1 = o_S0 + SZ_S;
  size_t o_H0 = o_S1 + SZ_S;
  size_t o_H1 = o_H0 + SZ_M;
  size_t o_Ut = o_H1 + SZ_M;
  size_t o_Xrh = o_Ut + SZ_M;
  size_t o_nh0 = o_Xrh + SZ_M;
  size_t o_YB = o_nh0 + SZ_M;
  size_t o_YX123 = o_YB + 4 * SZ_M;
  size_t o_X0c = o_YX123;
  size_t o_YS = o_X0c + SZ_MS;
  size_t o_Wg0t = o_YX123 + 3 * SZ_M;
  size_t o_Wc0t = o_Wg0t + (size_t)256 * 800 * 2;
  size_t o_Wg1t = o_Wc0t + (size_t)128 * 800 * 2;
  size_t o_Wc1t = o_Wg1t + (size_t)256 * 1280 * 2;
  size_t o_rinv = o_Wc1t + (size_t)128 * 1280 * 2;
  size_t o_cinv = o_rinv + NP * 4;
  size_t o_rs = o_cinv + NP * 4;
  size_t o_part = o_rs + NP * 4;
  size_t NEED = o_part + (size_t)8 * NP * 4;

  if (ws_size < NEED) {
    float v = -(float)(double)(ws_size >> 20);
    k_bail<<<(out_size + 255) / 256, 256, 0, stream>>>(out, out_size, v);
    return;
  }

  char* w = (char*)d_ws;
  short* S0 = (short*)(w + o_S0);
  short* S1 = (short*)(w + o_S1);
  short* H0 = (short*)(w + o_H0);
  short* H1 = (short*)(w + o_H1);
  short* Ut = (short*)(w + o_Ut);
  short* Xrh = (short*)(w + o_Xrh);
  short* nh0 = (short*)(w + o_nh0);
  short* nh1 = Ut;
  short* YB[4];
  for (int i = 0; i < 4; i++) YB[i] = (short*)(w + o_YB + i * SZ_M);
  short* YXa = H0;
  short* YXb = (short*)(w + o_YX123 + 0 * SZ_M);
  short* YXc = (short*)(w + o_YX123 + 1 * SZ_M);
  short* YXd = (short*)(w + o_YX123 + 2 * SZ_M);
  short* YS[4];
  for (int i = 0; i < 4; i++) YS[i] = (short*)(w + o_YS + i * SZ_MS);
  short* X0c = (short*)(w + o_X0c);
  short* Wg0t = (short*)(w + o_Wg0t);
  short* Wc0t = (short*)(w + o_Wc0t);
  short* Wg1t = (short*)(w + o_Wg1t);
  short* Wc1t = (short*)(w + o_Wc1t);
  float* rinv = (float*)(w + o_rinv);
  float* cinv = (float*)(w + o_cinv);
  float* rs = (float*)(w + o_rs);
  float* part = (float*)(w + o_part);

  k_rowsum<<<NN, 256, 0, stream>>>(adj, rs);
  k_colpart<<<dim3(16, 8), 256, 0, stream>>>(adj, part);
  k_inv<<<16, 256, 0, stream>>>(rs, part, rinv, cinv);
  k_supports<<<dim3(124, 124), dim3(32, 8), 0, stream>>>(adj, rinv, cinv, S0, S1);
  k_buildH<<<dim3(124, 4, 32), dim3(32, 8), 0, stream>>>(hid, H0, H1);
  k_buildX0c<<<dim3(31, 256), 128, 0, stream>>>(inp, X0c);
  k_buildWt<<<(256 * 800 + 255) / 256, 256, 0, stream>>>(Wg0, Wg0t, 256, 800, 32, 1);
  k_buildWt<<<(128 * 800 + 255) / 256, 256, 0, stream>>>(Wc0, Wc0t, 128, 800, 32, 1);
  k_buildWt<<<(256 * 1280 + 255) / 256, 256, 0, stream>>>(Wg1, Wg1t, 256, 1280, 128, 128);
  k_buildWt<<<(128 * 1280 + 255) / 256, 256, 0, stream>>>(Wc1, Wc1t, 128, 1280, 128, 128);

  auto launch_bt8 = [&](const Bt8Args& a, int nz) {
    k_gemm_bt8<<<dim3(8, 16, nz), 512, 0, stream>>>(a, S0, S1);
  };

  // ---- cell 0 ---- (X diffusion on compact 256-row X0c)
  {
    Bt8Args h1 = {{X0c, X0c, H0, H0}, {YS[0], YS[2], YB[0], YB[2]},
                  {nullptr, nullptr, nullptr, nullptr}, {256, 256, 2048, 2048}};
    launch_bt8(h1, 4);
    Bt8Args h2 = {{YS[0], YS[2], YB[0], YB[2]}, {YS[1], YS[3], YB[1], YB[3]},
                  {X0c, X0c, H0, H0}, {256, 256, 2048, 2048}};
    launch_bt8(h2, 4);
  }
  k_gemm_wt<<<dim3(31, 2, 16), 256, 0, stream>>>(Wg0t, 800, 160, 32, 1,
      X0c, YS[0], YS[1], YS[2], YS[3], H0, YB[0], YB[1], YB[2], YB[3],
      bg0, H0, Ut, Xrh, 0);
  {
    Bt8Args h1 = {{Xrh, Xrh, nullptr, nullptr}, {YB[0], YB[2], nullptr, nullptr},
                  {nullptr, nullptr, nullptr, nullptr}, {2048, 2048, 0, 0}};
    launch_bt8(h1, 2);
    Bt8Args h2 = {{YB[0], YB[2], nullptr, nullptr}, {YB[1], YB[3], nullptr, nullptr},
                  {Xrh, Xrh, nullptr, nullptr}, {2048, 2048, 0, 0}};
    launch_bt8(h2, 2);
  }
  k_gemm_wt<<<dim3(31, 1, 16), 256, 0, stream>>>(Wc0t, 800, 160, 32, 1,
      X0c, YS[0], YS[1], YS[2], YS[3], Xrh, YB[0], YB[1], YB[2], YB[3],
      bc0, H0, Ut, nh0, 1);

  // ---- cell 1 ----
  {
    Bt8Args h1 = {{nh0, nh0, H1, H1}, {YXa, YXc, YB[0], YB[2]},
                  {nullptr, nullptr, nullptr, nullptr}, {2048, 2048, 2048, 2048}};
    launch_bt8(h1, 4);
    Bt8Args h2 = {{YXa, YXc, YB[0], YB[2]}, {YXb, YXd, YB[1], YB[3]},
                  {nh0, nh0, H1, H1}, {2048, 2048, 2048, 2048}};
    launch_bt8(h2, 4);
  }
  k_gemm_wt<<<dim3(31, 2, 16), 256, 0, stream>>>(Wg1t, 1280, 640, 128, 128,
      nh0, YXa, YXb, YXc, YXd, H1, YB[0], YB[1], YB[2], YB[3],
      bg1, H1, Ut, Xrh, 0);
  {
    Bt8Args h1 = {{Xrh, Xrh, nullptr, nullptr}, {YB[0], YB[2], nullptr, nullptr},
                  {nullptr, nullptr, nullptr, nullptr}, {2048, 2048, 0, 0}};
    launch_bt8(h1, 2);
    Bt8Args h2 = {{YB[0], YB[2], nullptr, nullptr}, {YB[1], YB[3], nullptr, nullptr},
                  {Xrh, Xrh, nullptr, nullptr}, {2048, 2048, 0, 0}};
    launch_bt8(h2, 2);
  }
  k_gemm_wt<<<dim3(31, 1, 16), 256, 0, stream>>>(Wc1t, 1280, 640, 128, 128,
      nh0, YXa, YXb, YXc, YXd, Xrh, YB[0], YB[1], YB[2], YB[3],
      bc1, H1, Ut, nh1, 1);

  // ---- output projection ----
  k_proj<<<dim3(16, 16), 256, 0, stream>>>(nh1, Wp, bp, out);
}